// Round 1
// baseline (4841.489 us; speedup 1.0000x reference)
//
#include <hip/hip_runtime.h>

// Problem constants (match reference)
constexpr int NB   = 8;     // batches
constexpr int NC   = 64;    // channels
constexpr int NN   = 8192;  // points
constexpr int NM   = 2048;  // samples
constexpr int NK   = 16;    // knn
constexpr int NFPS = 1433;  // int(2048*0.7)
constexpr int NRAND = NM - NFPS; // 615

// JAX >= 0.4.36 defaults jax_threefry_partitionable=True. If validation fails
// with O(1) absmax, flip this to 0 (legacy odd/even-counter threefry scheme).
#define THREEFRY_PARTITIONABLE 1

// ---------------- workspace layout (bytes) ----------------
// [0,32)          : start[8]           (uint)
// [64,128)        : sub1[8] pairs      (uint x16)  shuffle round-1 subkeys
// [128,192)       : sub2[8] pairs      (uint x16)  shuffle round-2 subkeys
// [256, +64KB)    : idx[8][2048]       (int)
// [66048, +256KB) : v1[8][8192]        (uint)  round-1 permutation
// [328448,+1MB)   : knn[8][2048][16]   (int)
// [1377280,+16MB) : xT[8][8192][64]    (float) transposed x
constexpr size_t OFF_START = 0;
constexpr size_t OFF_SUB1  = 64;
constexpr size_t OFF_SUB2  = 128;
constexpr size_t OFF_IDX   = 256;
constexpr size_t OFF_V1    = 66048;
constexpr size_t OFF_KNN   = 328448;
constexpr size_t OFF_XT    = 1377280;

struct TF { unsigned a, b; };

__device__ __forceinline__ TF tf2(unsigned k0, unsigned k1, unsigned c0, unsigned c1) {
  unsigned ks2 = k0 ^ k1 ^ 0x1BD11BDAu;
  unsigned x0 = c0 + k0;
  unsigned x1 = c1 + k1;
#define TF_R(r) { x0 += x1; x1 = (x1 << r) | (x1 >> (32 - r)); x1 ^= x0; }
  TF_R(13) TF_R(15) TF_R(26) TF_R(6)
  x0 += k1;  x1 += ks2 + 1u;
  TF_R(17) TF_R(29) TF_R(16) TF_R(24)
  x0 += ks2; x1 += k0 + 2u;
  TF_R(13) TF_R(15) TF_R(26) TF_R(6)
  x0 += k0;  x1 += k1 + 3u;
  TF_R(17) TF_R(29) TF_R(16) TF_R(24)
  x0 += k1;  x1 += ks2 + 4u;
  TF_R(13) TF_R(15) TF_R(26) TF_R(6)
  x0 += ks2; x1 += k0 + 5u;
#undef TF_R
  TF r; r.a = x0; r.b = x1; return r;
}

// ---------------- PRNG setup (tiny, single thread) ----------------
__global__ void rng_setup(unsigned* __restrict__ startB,
                          unsigned* __restrict__ sub1,
                          unsigned* __restrict__ sub2) {
  if (threadIdx.x != 0) return;
  const unsigned K0 = 0u, K1 = 42u; // jax.random.key(42)
#if THREEFRY_PARTITIONABLE
  // keys[b] = H(key42; 0, b)
  for (int b = 0; b < NB; ++b) {
    TF kb = tf2(K0, K1, 0u, (unsigned)b);
    // randint: k1,k2 = split(key); lower = bits(k2); start = lower % 8192
    TF k2 = tf2(kb.a, kb.b, 0u, 1u);
    TF bt = tf2(k2.a, k2.b, 0u, 0u);
    startB[b] = (bt.a ^ bt.b) & (unsigned)(NN - 1);
  }
  TF keyr = tf2(K0, K1, 0u, 1u); // fold_in(key42, 1)
  for (int b = 0; b < NB; ++b) {
    TF rk = tf2(keyr.a, keyr.b, 0u, (unsigned)b);   // rkeys[b]
    TF s1 = tf2(rk.a, rk.b, 0u, 1u);                // round-1 subkey
    TF nk = tf2(rk.a, rk.b, 0u, 0u);                // round-1 carried key
    TF s2 = tf2(nk.a, nk.b, 0u, 1u);                // round-2 subkey
    sub1[2*b] = s1.a; sub1[2*b+1] = s1.b;
    sub2[2*b] = s2.a; sub2[2*b+1] = s2.b;
  }
#else
  // Legacy (non-partitionable) scheme: split uses iota(2n) halved.
  unsigned keysA[NB], keysB[NB];
  for (int j = 0; j < 4; ++j) {
    TF a = tf2(K0, K1, (unsigned)(2*j),   (unsigned)(2*j+8));
    TF c = tf2(K0, K1, (unsigned)(2*j+1), (unsigned)(2*j+9));
    keysA[j] = a.a; keysB[j] = c.a;
    keysA[j+4] = a.b; keysB[j+4] = c.b;
  }
  for (int b = 0; b < NB; ++b) {
    TF e = tf2(keysA[b], keysB[b], 0u, 2u);
    TF f = tf2(keysA[b], keysB[b], 1u, 3u);
    // k2 = row1 = (e.b, f.b); lower = bits(k2, scalar) = H0(k2;0,0)
    TF bt = tf2(e.b, f.b, 0u, 0u);
    startB[b] = bt.a & (unsigned)(NN - 1);
  }
  TF keyr = tf2(K0, K1, 0u, 1u); // fold_in same in both schemes
  unsigned rkA[NB], rkB[NB];
  for (int j = 0; j < 4; ++j) {
    TF a = tf2(keyr.a, keyr.b, (unsigned)(2*j),   (unsigned)(2*j+8));
    TF c = tf2(keyr.a, keyr.b, (unsigned)(2*j+1), (unsigned)(2*j+9));
    rkA[j] = a.a; rkB[j] = c.a;
    rkA[j+4] = a.b; rkB[j+4] = c.b;
  }
  for (int b = 0; b < NB; ++b) {
    TF e = tf2(rkA[b], rkB[b], 0u, 2u);
    TF f = tf2(rkA[b], rkB[b], 1u, 3u);
    sub1[2*b] = e.b; sub1[2*b+1] = f.b;     // subkey = row1
    unsigned nkA = e.a, nkB = f.a;          // carried key = row0
    TF e2 = tf2(nkA, nkB, 0u, 2u);
    TF f2 = tf2(nkA, nkB, 1u, 3u);
    sub2[2*b] = e2.b; sub2[2*b+1] = f2.b;
  }
#endif
}

// ---------------- FPS: one block per batch ----------------
#define FPS_BCAST(IDXV)                                              \
  do {                                                               \
    if (tid == ((IDXV) & 1023)) {                                    \
      int slot_ = (IDXV) >> 10; float xx, yy, zz;                    \
      switch (slot_) {                                               \
        case 0: xx=px[0]; yy=py[0]; zz=pz[0]; break;                 \
        case 1: xx=px[1]; yy=py[1]; zz=pz[1]; break;                 \
        case 2: xx=px[2]; yy=py[2]; zz=pz[2]; break;                 \
        case 3: xx=px[3]; yy=py[3]; zz=pz[3]; break;                 \
        case 4: xx=px[4]; yy=py[4]; zz=pz[4]; break;                 \
        case 5: xx=px[5]; yy=py[5]; zz=pz[5]; break;                 \
        case 6: xx=px[6]; yy=py[6]; zz=pz[6]; break;                 \
        default: xx=px[7]; yy=py[7]; zz=pz[7]; break;                \
      }                                                              \
      bc0 = xx; bc1 = yy; bc2 = zz;                                  \
    }                                                                \
  } while (0)

__global__ __launch_bounds__(1024) void fps_kernel(const float* __restrict__ pos,
                                                   const unsigned* __restrict__ startB,
                                                   int* __restrict__ idx) {
  __shared__ float rv[16];
  __shared__ int   ri[16];
  __shared__ float bc0, bc1, bc2;
  const int b = blockIdx.x;
  const int tid = threadIdx.x;
  const float* pb = pos + (size_t)b * 3 * NN;
  float px[8], py[8], pz[8], dist[8];
#pragma unroll
  for (int s = 0; s < 8; ++s) {
    int p = tid + (s << 10);
    px[s] = pb[p];
    py[s] = pb[NN + p];
    pz[s] = pb[2 * NN + p];
    dist[s] = 1e10f;
  }
  int cur = (int)startB[b];
  if (tid == 0) idx[b * NM] = cur;
  FPS_BCAST(cur);
  __syncthreads();
  for (int it = 1; it < NFPS; ++it) {
    const float cx = bc0, cy = bc1, cz = bc2;
    float bestv = -1.0f;
    int   besti = 0;
#pragma unroll
    for (int s = 0; s < 8; ++s) {
      // Mirror XLA exactly: no FMA contraction, ((dx2+dy2)+dz2)
      float dx = __fsub_rn(px[s], cx);
      float dy = __fsub_rn(py[s], cy);
      float dz = __fsub_rn(pz[s], cz);
      float d  = __fadd_rn(__fadd_rn(__fmul_rn(dx, dx), __fmul_rn(dy, dy)),
                           __fmul_rn(dz, dz));
      float nd = fminf(dist[s], d);
      dist[s] = nd;
      if (nd > bestv) { bestv = nd; besti = tid + (s << 10); }  // strict > keeps first index
    }
#pragma unroll
    for (int off = 1; off < 64; off <<= 1) {
      float ov = __shfl_xor(bestv, off, 64);
      int   oi = __shfl_xor(besti, off, 64);
      if (ov > bestv || (ov == bestv && oi < besti)) { bestv = ov; besti = oi; }
    }
    if ((tid & 63) == 0) { rv[tid >> 6] = bestv; ri[tid >> 6] = besti; }
    __syncthreads();
    float wv = rv[0]; int wi = ri[0];
#pragma unroll
    for (int q = 1; q < 16; ++q) {
      float v = rv[q]; int ii = ri[q];
      if (v > wv || (v == wv && ii < wi)) { wv = v; wi = ii; }
    }
    if (tid == 0) idx[b * NM + it] = wi;
    FPS_BCAST(wi);
    __syncthreads();
  }
}

// ---------------- permutation: 2 stable sorts by random u32 keys ----------------
__device__ void bitonic8192(unsigned long long* s, int tid) {
  for (unsigned k = 2; k <= 8192u; k <<= 1) {
    for (unsigned j = k >> 1; j > 0; j >>= 1) {
      __syncthreads();
      for (unsigned t = (unsigned)tid; t < 4096u; t += 1024u) {
        unsigned i = ((t & ~(j - 1u)) << 1) | (t & (j - 1u));
        unsigned p = i | j;
        bool up = ((i & k) == 0u);
        unsigned long long a = s[i], c = s[p];
        if ((a > c) == up) { s[i] = c; s[p] = a; }
      }
    }
  }
  __syncthreads();
}

__global__ __launch_bounds__(1024) void perm_kernel(const unsigned* __restrict__ sub1,
                                                    const unsigned* __restrict__ sub2,
                                                    unsigned* __restrict__ v1buf,
                                                    int* __restrict__ idx) {
  __shared__ unsigned long long s[NN]; // 64 KB
  const int b = blockIdx.x;
  const int tid = threadIdx.x;
  unsigned* v1 = v1buf + (size_t)b * NN;
  const unsigned k1a = sub1[2*b], k1b = sub1[2*b+1];
  // round 1: composite (sort_key << 32) | position  => stable sort
#if THREEFRY_PARTITIONABLE
  for (int i = tid; i < NN; i += 1024) {
    TF r = tf2(k1a, k1b, 0u, (unsigned)i);
    s[i] = ((unsigned long long)(r.a ^ r.b) << 32) | (unsigned)i;
  }
#else
  for (int i = tid; i < NN / 2; i += 1024) {
    TF r = tf2(k1a, k1b, (unsigned)i, (unsigned)(i + NN / 2));
    s[i]          = ((unsigned long long)r.a << 32) | (unsigned)i;
    s[i + NN / 2] = ((unsigned long long)r.b << 32) | (unsigned)(i + NN / 2);
  }
#endif
  bitonic8192(s, tid);
  for (int i = tid; i < NN; i += 1024) v1[i] = (unsigned)(s[i] & 0xffffffffu);
  __syncthreads();
  const unsigned k2a = sub2[2*b], k2b = sub2[2*b+1];
#if THREEFRY_PARTITIONABLE
  for (int i = tid; i < NN; i += 1024) {
    TF r = tf2(k2a, k2b, 0u, (unsigned)i);
    s[i] = ((unsigned long long)(r.a ^ r.b) << 32) | (unsigned)i;
  }
#else
  for (int i = tid; i < NN / 2; i += 1024) {
    TF r = tf2(k2a, k2b, (unsigned)i, (unsigned)(i + NN / 2));
    s[i]          = ((unsigned long long)r.a << 32) | (unsigned)i;
    s[i + NN / 2] = ((unsigned long long)r.b << 32) | (unsigned)(i + NN / 2);
  }
#endif
  bitonic8192(s, tid);
  for (int t = tid; t < NRAND; t += 1024) {
    unsigned p = (unsigned)(s[t] & 0xffffffffu);
    idx[b * NM + NFPS + t] = (int)v1[p];
  }
}

// ---------------- pos_sub gather ----------------
__global__ void possub_kernel(const float* __restrict__ pos,
                              const int* __restrict__ idx,
                              float* __restrict__ posOut) {
  int i = blockIdx.x * 256 + threadIdx.x;
  if (i >= NB * 3 * NM) return;
  int mm = i & (NM - 1);
  int bd = i >> 11;            // b*3 + d
  int d = bd % 3, b = bd / 3;
  posOut[i] = pos[((size_t)b * 3 + d) * NN + idx[b * NM + mm]];
}

// ---------------- transpose x [B,C,N] -> xT [B,N,C] ----------------
__global__ void transpose_kernel(const float* __restrict__ x, float* __restrict__ xT) {
  __shared__ float t[32][33];
  int b = blockIdx.z;
  int n0 = blockIdx.x * 32, c0 = blockIdx.y * 32;
  int tx = threadIdx.x, ty = threadIdx.y;
  t[ty][tx] = x[((size_t)b * NC + (c0 + ty)) * NN + n0 + tx];
  __syncthreads();
  xT[((size_t)b * NN + (n0 + ty)) * NC + c0 + tx] = t[tx][ty];
}

// ---------------- KNN: one wave per sampled point ----------------
__global__ __launch_bounds__(256) void knn_kernel(const float* __restrict__ pos,
                                                  const float* __restrict__ posSub,
                                                  int* __restrict__ knn) {
  __shared__ unsigned long long lst[4][NK][64]; // [wave][rank][lane], 32 KB
  const int tid = threadIdx.x;
  const int wv = tid >> 6, lane = tid & 63;
  const int g = blockIdx.x * 4 + wv;            // 0..16383
  const int b = g >> 11, mm = g & (NM - 1);
  const float* pb = pos + (size_t)b * 3 * NN;
  const float* ps = posSub + (size_t)b * 3 * NM;
  const float sx = ps[mm], sy = ps[NM + mm], sz = ps[2 * NM + mm];
  const float sm = __fadd_rn(__fadd_rn(__fmul_rn(sx, sx), __fmul_rn(sy, sy)),
                             __fmul_rn(sz, sz));
#pragma unroll
  for (int p = 0; p < NK; ++p) lst[wv][p][lane] = ~0ull;
  for (int t = 0; t < NN / 64; ++t) {
    const int n = t * 64 + lane;
    float x = pb[n], y = pb[NN + n], z = pb[2 * NN + n];
    float sn = __fadd_rn(__fadd_rn(__fmul_rn(x, x), __fmul_rn(y, y)), __fmul_rn(z, z));
    float dt = __fadd_rn(__fadd_rn(__fmul_rn(sx, x), __fmul_rn(sy, y)), __fmul_rn(sz, z));
    float d2 = __fsub_rn(__fadd_rn(sm, sn), __fmul_rn(2.0f, dt)); // mirror reference
    unsigned u = __float_as_uint(d2);
    u = (u & 0x80000000u) ? ~u : (u | 0x80000000u); // order-preserving f32->u32
    unsigned long long comp = ((unsigned long long)u << 32) | (unsigned)n;
    if (comp < lst[wv][NK - 1][lane]) {
      int p = NK - 1;
      while (p > 0) {
        unsigned long long prev = lst[wv][p - 1][lane];
        if (prev <= comp) break;
        lst[wv][p][lane] = prev;
        --p;
      }
      lst[wv][p][lane] = comp;
    }
  }
  // merge 64 sorted lists: 16 rounds of wave-min; unique composites => safe pop
  int ptr = 0;
  unsigned long long head = lst[wv][0][lane];
  unsigned myn = 0;
  for (int k = 0; k < NK; ++k) {
    unsigned long long mn = head;
#pragma unroll
    for (int off = 32; off > 0; off >>= 1) {
      unsigned long long o = __shfl_xor(mn, off, 64);
      if (o < mn) mn = o;
    }
    if (head == mn) { ++ptr; head = (ptr < NK) ? lst[wv][ptr][lane] : ~0ull; }
    if (lane == k) myn = (unsigned)(mn & 0xffffffffu);
  }
  if (lane < NK) knn[(size_t)g * NK + lane] = (int)myn;
}

// ---------------- weights + gather + weighted sum ----------------
__global__ __launch_bounds__(256) void final_kernel(const float* __restrict__ xT,
                                                    const float* __restrict__ pos,
                                                    const float* __restrict__ posSub,
                                                    const int* __restrict__ knn,
                                                    float* __restrict__ xOut) {
  __shared__ float tile[64][17];
  const int tid = threadIdx.x;
  const int wv = tid >> 6, lane = tid & 63;
  const int base = blockIdx.x * 16;      // 16 consecutive samples, same batch
  const int b = base >> 11;
  const float* pb = pos + (size_t)b * 3 * NN;
  const float* ps = posSub + (size_t)b * 3 * NM;
  for (int j = 0; j < 4; ++j) {
    const int ml = wv * 4 + j;           // 0..15
    const int g = base + ml;
    const int mm = g & (NM - 1);
    const float sx = ps[mm], sy = ps[NM + mm], sz = ps[2 * NM + mm];
    const int kk = lane & 15;
    const int nk = knn[(size_t)g * NK + kk];
    float dx = __fsub_rn(pb[nk], sx);
    float dy = __fsub_rn(pb[NN + nk], sy);
    float dz = __fsub_rn(pb[2 * NN + nk], sz);
    float dd = __fadd_rn(__fadd_rn(__fmul_rn(dx, dx), __fmul_rn(dy, dy)),
                         __fmul_rn(dz, dz));
    float d = __fsqrt_rn(dd);
    d = fmaxf(d, 1e-6f);
    float e = __fdiv_rn(0.0f - d, 0.2f);
    float mx = e;
#pragma unroll
    for (int off = 8; off > 0; off >>= 1) mx = fmaxf(mx, __shfl_xor(mx, off, 16));
    float ex = expf(__fsub_rn(e, mx));
    float sum = ex;
#pragma unroll
    for (int off = 8; off > 0; off >>= 1) sum = __fadd_rn(sum, __shfl_xor(sum, off, 16));
    float wgt = __fdiv_rn(ex, sum);
    float acc = 0.0f;
#pragma unroll
    for (int k = 0; k < NK; ++k) {
      float wk = __shfl(wgt, k, 64);
      int   nn = __shfl(nk, k, 64);
      acc = __fadd_rn(acc, __fmul_rn(wk, xT[((size_t)b * NN + nn) * NC + lane]));
    }
    tile[lane][ml] = acc;
  }
  __syncthreads();
  const int m0 = base & (NM - 1);
  for (int e2 = tid; e2 < 64 * 16; e2 += 256) {
    int c = e2 >> 4, ml = e2 & 15;
    xOut[((size_t)b * NC + c) * NM + m0 + ml] = tile[c][ml];
  }
}

extern "C" void kernel_launch(void* const* d_in, const int* in_sizes, int n_in,
                              void* d_out, int out_size, void* d_ws, size_t ws_size,
                              hipStream_t stream) {
  const float* x   = (const float*)d_in[0];
  const float* pos = (const float*)d_in[1];
  float* xOut   = (float*)d_out;
  float* posOut = xOut + (size_t)NB * NC * NM;

  char* w = (char*)d_ws;
  unsigned* startB = (unsigned*)(w + OFF_START);
  unsigned* sub1   = (unsigned*)(w + OFF_SUB1);
  unsigned* sub2   = (unsigned*)(w + OFF_SUB2);
  int*      idx    = (int*)(w + OFF_IDX);
  unsigned* v1     = (unsigned*)(w + OFF_V1);
  int*      knn    = (int*)(w + OFF_KNN);
  float*    xT     = (float*)(w + OFF_XT);

  hipLaunchKernelGGL(rng_setup, dim3(1), dim3(64), 0, stream, startB, sub1, sub2);
  hipLaunchKernelGGL(fps_kernel, dim3(NB), dim3(1024), 0, stream, pos, startB, idx);
  hipLaunchKernelGGL(perm_kernel, dim3(NB), dim3(1024), 0, stream, sub1, sub2, v1, idx);
  hipLaunchKernelGGL(possub_kernel, dim3((NB * 3 * NM + 255) / 256), dim3(256), 0, stream,
                     pos, idx, posOut);
  hipLaunchKernelGGL(transpose_kernel, dim3(NN / 32, NC / 32, NB), dim3(32, 32), 0, stream,
                     x, xT);
  hipLaunchKernelGGL(knn_kernel, dim3(NB * NM / 4), dim3(256), 0, stream, pos, posOut, knn);
  hipLaunchKernelGGL(final_kernel, dim3(NB * NM / 16), dim3(256), 0, stream,
                     xT, pos, posOut, knn, xOut);
}

// Round 2
// 2849.360 us; speedup vs baseline: 1.6991x; 1.6991x over previous
//
#include <hip/hip_runtime.h>

// Problem constants (match reference)
constexpr int NB   = 8;     // batches
constexpr int NC   = 64;    // channels
constexpr int NN   = 8192;  // points
constexpr int NM   = 2048;  // samples
constexpr int NK   = 16;    // knn
constexpr int NFPS = 1433;  // int(2048*0.7)
constexpr int NRAND = NM - NFPS; // 615

// ---------------- workspace layout (bytes) ----------------
constexpr size_t OFF_START = 0;
constexpr size_t OFF_SUB1  = 64;
constexpr size_t OFF_SUB2  = 128;
constexpr size_t OFF_IDX   = 256;      // int idx[8][2048]
constexpr size_t OFF_V1    = 66048;    // uint v1[8][8192]
constexpr size_t OFF_KNN   = 328448;   // int knn[8][2048][16]
constexpr size_t OFF_XT    = 1377280;  // float xT[8][8192][64]

struct TF { unsigned a, b; };

__device__ __forceinline__ TF tf2(unsigned k0, unsigned k1, unsigned c0, unsigned c1) {
  unsigned ks2 = k0 ^ k1 ^ 0x1BD11BDAu;
  unsigned x0 = c0 + k0;
  unsigned x1 = c1 + k1;
#define TF_R(r) { x0 += x1; x1 = (x1 << r) | (x1 >> (32 - r)); x1 ^= x0; }
  TF_R(13) TF_R(15) TF_R(26) TF_R(6)
  x0 += k1;  x1 += ks2 + 1u;
  TF_R(17) TF_R(29) TF_R(16) TF_R(24)
  x0 += ks2; x1 += k0 + 2u;
  TF_R(13) TF_R(15) TF_R(26) TF_R(6)
  x0 += k0;  x1 += k1 + 3u;
  TF_R(17) TF_R(29) TF_R(16) TF_R(24)
  x0 += k1;  x1 += ks2 + 4u;
  TF_R(13) TF_R(15) TF_R(26) TF_R(6)
  x0 += ks2; x1 += k0 + 5u;
#undef TF_R
  TF r; r.a = x0; r.b = x1; return r;
}

// ---------------- PRNG setup (tiny, single thread) ----------------
// jax_threefry_partitionable=True semantics (verified passing in R1).
__global__ void rng_setup(unsigned* __restrict__ startB,
                          unsigned* __restrict__ sub1,
                          unsigned* __restrict__ sub2) {
  if (threadIdx.x != 0) return;
  const unsigned K0 = 0u, K1 = 42u; // jax.random.key(42)
  for (int b = 0; b < NB; ++b) {
    TF kb = tf2(K0, K1, 0u, (unsigned)b);
    TF k2 = tf2(kb.a, kb.b, 0u, 1u);
    TF bt = tf2(k2.a, k2.b, 0u, 0u);
    startB[b] = (bt.a ^ bt.b) & (unsigned)(NN - 1);
  }
  TF keyr = tf2(K0, K1, 0u, 1u); // fold_in(key42, 1)
  for (int b = 0; b < NB; ++b) {
    TF rk = tf2(keyr.a, keyr.b, 0u, (unsigned)b);   // rkeys[b]
    TF s1 = tf2(rk.a, rk.b, 0u, 1u);                // round-1 subkey
    TF nk = tf2(rk.a, rk.b, 0u, 0u);                // round-1 carried key
    TF s2 = tf2(nk.a, nk.b, 0u, 1u);                // round-2 subkey
    sub1[2*b] = s1.a; sub1[2*b+1] = s1.b;
    sub2[2*b] = s2.a; sub2[2*b+1] = s2.b;
  }
}

// ---------------- FPS: one block (256 thr) per batch ----------------
// Latency-chain kernel: 1432 serial argmax steps. Structure per step:
//   uniform coord load (L1/L2) -> 32-pt register update -> u64 wave max
//   -> 1-of-4 LDS slot write -> ONE barrier (slots double-buffered).
__global__ __launch_bounds__(256) void fps_kernel(const float* __restrict__ pos,
                                                  const unsigned* __restrict__ startB,
                                                  int* __restrict__ idx) {
  __shared__ unsigned long long slot[2][4];
  const int b = blockIdx.x;
  const int tid = threadIdx.x;
  const int wv = tid >> 6, lane = tid & 63;
  const float* pb = pos + (size_t)b * 3 * NN;
  float px[32], py[32], pz[32], dist[32];
  const int base = tid * 32;   // lane-contiguous point ownership
  const float4* fx = (const float4*)(pb + base);
  const float4* fy = (const float4*)(pb + NN + base);
  const float4* fz = (const float4*)(pb + 2 * NN + base);
#pragma unroll
  for (int q = 0; q < 8; ++q) {
    float4 a = fx[q], c = fy[q], e = fz[q];
    px[4*q] = a.x; px[4*q+1] = a.y; px[4*q+2] = a.z; px[4*q+3] = a.w;
    py[4*q] = c.x; py[4*q+1] = c.y; py[4*q+2] = c.z; py[4*q+3] = c.w;
    pz[4*q] = e.x; pz[4*q+1] = e.y; pz[4*q+2] = e.z; pz[4*q+3] = e.w;
  }
#pragma unroll
  for (int s = 0; s < 32; ++s) dist[s] = 1e10f;
  int widx = (int)startB[b];
  if (tid == 0) idx[b * NM] = widx;
  for (int it = 1; it < NFPS; ++it) {
    const int u = __builtin_amdgcn_readfirstlane(widx);
    const float cx = pb[u], cy = pb[NN + u], cz = pb[2 * NN + u];
    float bestv = -1.0f; int bestS = 0;
#pragma unroll
    for (int s = 0; s < 32; ++s) {
      // Mirror XLA exactly: rn ops, no FMA contraction, ((dx2+dy2)+dz2)
      float dx = __fsub_rn(px[s], cx);
      float dy = __fsub_rn(py[s], cy);
      float dz = __fsub_rn(pz[s], cz);
      float d  = __fadd_rn(__fadd_rn(__fmul_rn(dx, dx), __fmul_rn(dy, dy)),
                           __fmul_rn(dz, dz));
      float nd = fminf(dist[s], d);
      dist[s] = nd;
      if (nd > bestv) { bestv = nd; bestS = s; } // strict > keeps first index
    }
    // pack: max key == max dist, tie -> smallest global index (argmax semantics)
    unsigned long long key = ((unsigned long long)__float_as_uint(bestv) << 13)
                           | (unsigned)(8191 - (base + bestS));
#pragma unroll
    for (int off = 1; off < 64; off <<= 1) {
      unsigned long long o = __shfl_xor(key, off, 64);
      if (o > key) key = o;
    }
    if (lane == 0) slot[it & 1][wv] = key;
    __syncthreads();
    unsigned long long k0 = slot[it & 1][0], k1 = slot[it & 1][1];
    unsigned long long k2 = slot[it & 1][2], k3 = slot[it & 1][3];
    if (k1 > k0) k0 = k1;
    if (k3 > k2) k2 = k3;
    if (k2 > k0) k0 = k2;
    widx = 8191 - (int)(k0 & 8191u);
    if (tid == 0) idx[b * NM + it] = widx;
  }
}

// ---------------- permutation: 2 independent stable sorts, 16 blocks ----------------
__device__ void bitonic8192(unsigned long long* s, int tid) {
  for (unsigned k = 2; k <= 8192u; k <<= 1) {
    for (unsigned j = k >> 1; j > 0; j >>= 1) {
      __syncthreads();
      for (unsigned t = (unsigned)tid; t < 4096u; t += 1024u) {
        unsigned i = ((t & ~(j - 1u)) << 1) | (t & (j - 1u));
        unsigned p = i | j;
        bool up = ((i & k) == 0u);
        unsigned long long a = s[i], c = s[p];
        if ((a > c) == up) { s[i] = c; s[p] = a; }
      }
    }
  }
  __syncthreads();
}

// block = (batch, round). Round 0 writes the full round-1 permutation v1;
// round 1 writes its first NRAND payload positions into idx (composed later).
__global__ __launch_bounds__(1024) void perm_kernel(const unsigned* __restrict__ sub1,
                                                    const unsigned* __restrict__ sub2,
                                                    unsigned* __restrict__ v1buf,
                                                    int* __restrict__ idx) {
  __shared__ unsigned long long s[NN]; // 64 KB
  const int bl = blockIdx.x;
  const int b = bl >> 1, r = bl & 1;
  const int tid = threadIdx.x;
  const unsigned* sk = (r == 0) ? sub1 : sub2;
  const unsigned ka = sk[2*b], kb = sk[2*b+1];
  for (int i = tid; i < NN; i += 1024) {
    TF t = tf2(ka, kb, 0u, (unsigned)i);
    // composite (key<<32)|position => stable sort incl. key collisions
    s[i] = ((unsigned long long)(t.a ^ t.b) << 32) | (unsigned)i;
  }
  bitonic8192(s, tid);
  if (r == 0) {
    unsigned* v1 = v1buf + (size_t)b * NN;
    for (int i = tid; i < NN; i += 1024) v1[i] = (unsigned)(s[i] & 0xffffffffu);
  } else {
    for (int t = tid; t < NRAND; t += 1024)
      idx[b * NM + NFPS + t] = (int)(s[t] & 0xffffffffu);
  }
}

// ---------------- pos_sub gather (composes v1[v2] for the random part) ----------------
__global__ void possub_kernel(const float* __restrict__ pos,
                              const int* __restrict__ idx,
                              const unsigned* __restrict__ v1,
                              float* __restrict__ posOut) {
  int i = blockIdx.x * 256 + threadIdx.x;
  if (i >= NB * 3 * NM) return;
  int mm = i & (NM - 1);
  int bd = i >> 11;            // b*3 + d
  int d = bd % 3, b = bd / 3;
  int raw = idx[b * NM + mm];
  int id = (mm < NFPS) ? raw : (int)v1[(size_t)b * NN + raw];
  posOut[i] = pos[((size_t)b * 3 + d) * NN + id];
}

// ---------------- transpose x [B,C,N] -> xT [B,N,C] ----------------
__global__ void transpose_kernel(const float* __restrict__ x, float* __restrict__ xT) {
  __shared__ float t[32][33];
  int b = blockIdx.z;
  int n0 = blockIdx.x * 32, c0 = blockIdx.y * 32;
  int tx = threadIdx.x, ty = threadIdx.y;
  t[ty][tx] = x[((size_t)b * NC + (c0 + ty)) * NN + n0 + tx];
  __syncthreads();
  xT[((size_t)b * NN + (n0 + ty)) * NC + c0 + tx] = t[tx][ty];
}

// ---------------- KNN: one wave per sampled point ----------------
__global__ __launch_bounds__(256) void knn_kernel(const float* __restrict__ pos,
                                                  const float* __restrict__ posSub,
                                                  int* __restrict__ knn) {
  __shared__ unsigned long long lst[4][NK][64]; // [wave][rank][lane], 32 KB
  const int tid = threadIdx.x;
  const int wv = tid >> 6, lane = tid & 63;
  const int g = blockIdx.x * 4 + wv;            // 0..16383
  const int b = g >> 11, mm = g & (NM - 1);
  const float* pb = pos + (size_t)b * 3 * NN;
  const float* ps = posSub + (size_t)b * 3 * NM;
  const float sx = ps[mm], sy = ps[NM + mm], sz = ps[2 * NM + mm];
  const float sm = __fadd_rn(__fadd_rn(__fmul_rn(sx, sx), __fmul_rn(sy, sy)),
                             __fmul_rn(sz, sz));
#pragma unroll
  for (int p = 0; p < NK; ++p) lst[wv][p][lane] = ~0ull;
  for (int t = 0; t < NN / 64; ++t) {
    const int n = t * 64 + lane;
    float x = pb[n], y = pb[NN + n], z = pb[2 * NN + n];
    float sn = __fadd_rn(__fadd_rn(__fmul_rn(x, x), __fmul_rn(y, y)), __fmul_rn(z, z));
    float dt = __fadd_rn(__fadd_rn(__fmul_rn(sx, x), __fmul_rn(sy, y)), __fmul_rn(sz, z));
    float d2 = __fsub_rn(__fadd_rn(sm, sn), __fmul_rn(2.0f, dt)); // mirror reference
    unsigned u = __float_as_uint(d2);
    u = (u & 0x80000000u) ? ~u : (u | 0x80000000u); // order-preserving f32->u32
    unsigned long long comp = ((unsigned long long)u << 32) | (unsigned)n;
    if (comp < lst[wv][NK - 1][lane]) {
      int p = NK - 1;
      while (p > 0) {
        unsigned long long prev = lst[wv][p - 1][lane];
        if (prev <= comp) break;
        lst[wv][p][lane] = prev;
        --p;
      }
      lst[wv][p][lane] = comp;
    }
  }
  // merge 64 sorted lists: 16 rounds of wave-min; unique composites => safe pop
  int ptr = 0;
  unsigned long long head = lst[wv][0][lane];
  unsigned myn = 0;
  for (int k = 0; k < NK; ++k) {
    unsigned long long mn = head;
#pragma unroll
    for (int off = 32; off > 0; off >>= 1) {
      unsigned long long o = __shfl_xor(mn, off, 64);
      if (o < mn) mn = o;
    }
    if (head == mn) { ++ptr; head = (ptr < NK) ? lst[wv][ptr][lane] : ~0ull; }
    if (lane == k) myn = (unsigned)(mn & 0xffffffffu);
  }
  if (lane < NK) knn[(size_t)g * NK + lane] = (int)myn;
}

// ---------------- weights + gather + weighted sum ----------------
__global__ __launch_bounds__(256) void final_kernel(const float* __restrict__ xT,
                                                    const float* __restrict__ pos,
                                                    const float* __restrict__ posSub,
                                                    const int* __restrict__ knn,
                                                    float* __restrict__ xOut) {
  __shared__ float tile[64][17];
  const int tid = threadIdx.x;
  const int wv = tid >> 6, lane = tid & 63;
  const int base = blockIdx.x * 16;      // 16 consecutive samples, same batch
  const int b = base >> 11;
  const float* pb = pos + (size_t)b * 3 * NN;
  const float* ps = posSub + (size_t)b * 3 * NM;
  for (int j = 0; j < 4; ++j) {
    const int ml = wv * 4 + j;           // 0..15
    const int g = base + ml;
    const int mm = g & (NM - 1);
    const float sx = ps[mm], sy = ps[NM + mm], sz = ps[2 * NM + mm];
    const int kk = lane & 15;
    const int nk = knn[(size_t)g * NK + kk];
    float dx = __fsub_rn(pb[nk], sx);
    float dy = __fsub_rn(pb[NN + nk], sy);
    float dz = __fsub_rn(pb[2 * NN + nk], sz);
    float dd = __fadd_rn(__fadd_rn(__fmul_rn(dx, dx), __fmul_rn(dy, dy)),
                         __fmul_rn(dz, dz));
    float d = __fsqrt_rn(dd);
    d = fmaxf(d, 1e-6f);
    float e = __fdiv_rn(0.0f - d, 0.2f);
    float mx = e;
#pragma unroll
    for (int off = 8; off > 0; off >>= 1) mx = fmaxf(mx, __shfl_xor(mx, off, 16));
    float ex = expf(__fsub_rn(e, mx));
    float sum = ex;
#pragma unroll
    for (int off = 8; off > 0; off >>= 1) sum = __fadd_rn(sum, __shfl_xor(sum, off, 16));
    float wgt = __fdiv_rn(ex, sum);
    float acc = 0.0f;
#pragma unroll
    for (int k = 0; k < NK; ++k) {
      float wk = __shfl(wgt, k, 64);
      int   nn = __shfl(nk, k, 64);
      acc = __fadd_rn(acc, __fmul_rn(wk, xT[((size_t)b * NN + nn) * NC + lane]));
    }
    tile[lane][ml] = acc;
  }
  __syncthreads();
  const int m0 = base & (NM - 1);
  for (int e2 = tid; e2 < 64 * 16; e2 += 256) {
    int c = e2 >> 4, ml = e2 & 15;
    xOut[((size_t)b * NC + c) * NM + m0 + ml] = tile[c][ml];
  }
}

extern "C" void kernel_launch(void* const* d_in, const int* in_sizes, int n_in,
                              void* d_out, int out_size, void* d_ws, size_t ws_size,
                              hipStream_t stream) {
  const float* x   = (const float*)d_in[0];
  const float* pos = (const float*)d_in[1];
  float* xOut   = (float*)d_out;
  float* posOut = xOut + (size_t)NB * NC * NM;

  char* w = (char*)d_ws;
  unsigned* startB = (unsigned*)(w + OFF_START);
  unsigned* sub1   = (unsigned*)(w + OFF_SUB1);
  unsigned* sub2   = (unsigned*)(w + OFF_SUB2);
  int*      idx    = (int*)(w + OFF_IDX);
  unsigned* v1     = (unsigned*)(w + OFF_V1);
  int*      knn    = (int*)(w + OFF_KNN);
  float*    xT     = (float*)(w + OFF_XT);

  hipLaunchKernelGGL(rng_setup, dim3(1), dim3(64), 0, stream, startB, sub1, sub2);
  hipLaunchKernelGGL(fps_kernel, dim3(NB), dim3(256), 0, stream, pos, startB, idx);
  hipLaunchKernelGGL(perm_kernel, dim3(2 * NB), dim3(1024), 0, stream, sub1, sub2, v1, idx);
  hipLaunchKernelGGL(possub_kernel, dim3((NB * 3 * NM + 255) / 256), dim3(256), 0, stream,
                     pos, idx, v1, posOut);
  hipLaunchKernelGGL(transpose_kernel, dim3(NN / 32, NC / 32, NB), dim3(32, 32), 0, stream,
                     x, xT);
  hipLaunchKernelGGL(knn_kernel, dim3(NB * NM / 4), dim3(256), 0, stream, pos, posOut, knn);
  hipLaunchKernelGGL(final_kernel, dim3(NB * NM / 16), dim3(256), 0, stream,
                     xT, pos, posOut, knn, xOut);
}

// Round 3
// 2683.163 us; speedup vs baseline: 1.8044x; 1.0619x over previous
//
#include <hip/hip_runtime.h>

// Problem constants (match reference)
constexpr int NB   = 8;     // batches
constexpr int NC   = 64;    // channels
constexpr int NN   = 8192;  // points
constexpr int NM   = 2048;  // samples
constexpr int NK   = 16;    // knn
constexpr int NFPS = 1433;  // int(2048*0.7)
constexpr int NRAND = NM - NFPS; // 615

// ---------------- workspace layout (bytes) ----------------
constexpr size_t OFF_START = 0;
constexpr size_t OFF_SUB1  = 64;
constexpr size_t OFF_SUB2  = 128;
constexpr size_t OFF_IDX   = 256;      // int idx[8][2048]
constexpr size_t OFF_V1    = 66048;    // uint v1[8][8192]
constexpr size_t OFF_KNN   = 328448;   // int knn[8][2048][16]
constexpr size_t OFF_XT    = 1377280;  // float xT[8][8192][64]

struct TF { unsigned a, b; };

__device__ __forceinline__ TF tf2(unsigned k0, unsigned k1, unsigned c0, unsigned c1) {
  unsigned ks2 = k0 ^ k1 ^ 0x1BD11BDAu;
  unsigned x0 = c0 + k0;
  unsigned x1 = c1 + k1;
#define TF_R(r) { x0 += x1; x1 = (x1 << r) | (x1 >> (32 - r)); x1 ^= x0; }
  TF_R(13) TF_R(15) TF_R(26) TF_R(6)
  x0 += k1;  x1 += ks2 + 1u;
  TF_R(17) TF_R(29) TF_R(16) TF_R(24)
  x0 += ks2; x1 += k0 + 2u;
  TF_R(13) TF_R(15) TF_R(26) TF_R(6)
  x0 += k0;  x1 += k1 + 3u;
  TF_R(17) TF_R(29) TF_R(16) TF_R(24)
  x0 += k1;  x1 += ks2 + 4u;
  TF_R(13) TF_R(15) TF_R(26) TF_R(6)
  x0 += ks2; x1 += k0 + 5u;
#undef TF_R
  TF r; r.a = x0; r.b = x1; return r;
}

// ---------------- PRNG setup (jax_threefry_partitionable=True, verified R1) ----------------
__global__ void rng_setup(unsigned* __restrict__ startB,
                          unsigned* __restrict__ sub1,
                          unsigned* __restrict__ sub2) {
  if (threadIdx.x != 0) return;
  const unsigned K0 = 0u, K1 = 42u; // jax.random.key(42)
  for (int b = 0; b < NB; ++b) {
    TF kb = tf2(K0, K1, 0u, (unsigned)b);
    TF k2 = tf2(kb.a, kb.b, 0u, 1u);
    TF bt = tf2(k2.a, k2.b, 0u, 0u);
    startB[b] = (bt.a ^ bt.b) & (unsigned)(NN - 1);
  }
  TF keyr = tf2(K0, K1, 0u, 1u); // fold_in(key42, 1)
  for (int b = 0; b < NB; ++b) {
    TF rk = tf2(keyr.a, keyr.b, 0u, (unsigned)b);   // rkeys[b]
    TF s1 = tf2(rk.a, rk.b, 0u, 1u);                // round-1 subkey
    TF nk = tf2(rk.a, rk.b, 0u, 0u);                // round-1 carried key
    TF s2 = tf2(nk.a, nk.b, 0u, 1u);                // round-2 subkey
    sub1[2*b] = s1.a; sub1[2*b+1] = s1.b;
    sub2[2*b] = s2.a; sub2[2*b+1] = s2.b;
  }
}

// ---------------- FPS: one block (256 thr, 4 waves) per batch ----------------
// (256,1): allow up to 512 VGPR so the 128 resident floats stay in registers
// (R2's default-occupancy build spilled them into per-iteration L1 reloads).
// Winner coords ride the butterfly + LDS tournament -> no dependent global
// load on the critical path. One barrier/iter via parity double-buffer.
__global__ __launch_bounds__(256, 1) void fps_kernel(const float* __restrict__ pos,
                                                     const unsigned* __restrict__ startB,
                                                     int* __restrict__ idx) {
  __shared__ float4 slotA[2][4];  // {key.lo, key.hi, x, y}
  __shared__ float4 slotB[2][4];  // {z, -, -, -}
  const int b = blockIdx.x;
  const int tid = threadIdx.x;
  const int wv = tid >> 6, lane = tid & 63;
  const float* pb = pos + (size_t)b * 3 * NN;
  float px[32], py[32], pz[32], dist[32];
  const int base = tid * 32;   // tid-major ownership => lane order == index order
  const float4* fx = (const float4*)(pb + base);
  const float4* fy = (const float4*)(pb + NN + base);
  const float4* fz = (const float4*)(pb + 2 * NN + base);
#pragma unroll
  for (int q = 0; q < 8; ++q) {
    float4 a = fx[q], c = fy[q], e = fz[q];
    px[4*q] = a.x; px[4*q+1] = a.y; px[4*q+2] = a.z; px[4*q+3] = a.w;
    py[4*q] = c.x; py[4*q+1] = c.y; py[4*q+2] = c.z; py[4*q+3] = c.w;
    pz[4*q] = e.x; pz[4*q+1] = e.y; pz[4*q+2] = e.z; pz[4*q+3] = e.w;
  }
#pragma unroll
  for (int s = 0; s < 32; ++s) dist[s] = 1e10f;
  int widx = (int)startB[b];
  float cx = pb[widx], cy = pb[NN + widx], cz = pb[2 * NN + widx];
  if (tid == 0) idx[b * NM] = widx;
  for (int it = 1; it < NFPS; ++it) {
    const int par = it & 1;
    float bestv = -1.0f, bx = 0.f, by = 0.f, bz = 0.f;
    int bestS = 0;
#pragma unroll
    for (int s = 0; s < 32; ++s) {
      // Mirror numpy/XLA exactly: rn ops, no FMA contraction, ((dx2+dy2)+dz2)
      float dx = __fsub_rn(px[s], cx);
      float dy = __fsub_rn(py[s], cy);
      float dz = __fsub_rn(pz[s], cz);
      float d  = __fadd_rn(__fadd_rn(__fmul_rn(dx, dx), __fmul_rn(dy, dy)),
                           __fmul_rn(dz, dz));
      float nd = fminf(dist[s], d);
      dist[s] = nd;
      bool c = nd > bestv;            // strict > keeps first (smallest) index
      bestv = c ? nd : bestv;
      bestS = c ? s : bestS;
      bx = c ? px[s] : bx;
      by = c ? py[s] : by;
      bz = c ? pz[s] : bz;
    }
    // key: max dist wins, tie -> smallest global index (argmax semantics)
    unsigned long long key = ((unsigned long long)__float_as_uint(bestv) << 13)
                           | (unsigned)(8191 - (base + bestS));
    float wx = bx, wy = by, wz = bz;
#pragma unroll
    for (int off = 1; off < 64; off <<= 1) {
      unsigned long long o = __shfl_xor(key, off, 64);
      float ox = __shfl_xor(wx, off, 64);
      float oy = __shfl_xor(wy, off, 64);
      float oz = __shfl_xor(wz, off, 64);
      if (o > key) { key = o; wx = ox; wy = oy; wz = oz; }
    }
    if (lane == 0) {
      slotA[par][wv] = make_float4(__uint_as_float((unsigned)key),
                                   __uint_as_float((unsigned)(key >> 32)), wx, wy);
      slotB[par][wv] = make_float4(wz, 0.f, 0.f, 0.f);
    }
    __syncthreads();
    float4 a0 = slotA[par][0], a1 = slotA[par][1], a2 = slotA[par][2], a3 = slotA[par][3];
    float z0 = slotB[par][0].x, z1 = slotB[par][1].x, z2 = slotB[par][2].x, z3 = slotB[par][3].x;
    unsigned long long k0 = ((unsigned long long)__float_as_uint(a0.y) << 32) | __float_as_uint(a0.x);
    unsigned long long k1 = ((unsigned long long)__float_as_uint(a1.y) << 32) | __float_as_uint(a1.x);
    unsigned long long k2 = ((unsigned long long)__float_as_uint(a2.y) << 32) | __float_as_uint(a2.x);
    unsigned long long k3 = ((unsigned long long)__float_as_uint(a3.y) << 32) | __float_as_uint(a3.x);
    if (k1 > k0) { k0 = k1; a0 = a1; z0 = z1; }
    if (k3 > k2) { k2 = k3; a2 = a3; z2 = z3; }
    if (k2 > k0) { k0 = k2; a0 = a2; z0 = z2; }
    widx = 8191 - (int)(k0 & 8191u);
    cx = a0.z; cy = a0.w; cz = z0;
    if (tid == 0) idx[b * NM + it] = widx;
  }
}

// ---------------- permutation: 2 independent stable sorts, 16 blocks ----------------
__device__ void bitonic8192(unsigned long long* s, int tid) {
  for (unsigned k = 2; k <= 8192u; k <<= 1) {
    for (unsigned j = k >> 1; j > 0; j >>= 1) {
      __syncthreads();
      for (unsigned t = (unsigned)tid; t < 4096u; t += 1024u) {
        unsigned i = ((t & ~(j - 1u)) << 1) | (t & (j - 1u));
        unsigned p = i | j;
        bool up = ((i & k) == 0u);
        unsigned long long a = s[i], c = s[p];
        if ((a > c) == up) { s[i] = c; s[p] = a; }
      }
    }
  }
  __syncthreads();
}

// block = (batch, round). Round 0 writes the full round-1 permutation v1;
// round 1 writes its first NRAND payload positions into idx (composed later).
__global__ __launch_bounds__(1024) void perm_kernel(const unsigned* __restrict__ sub1,
                                                    const unsigned* __restrict__ sub2,
                                                    unsigned* __restrict__ v1buf,
                                                    int* __restrict__ idx) {
  __shared__ unsigned long long s[NN]; // 64 KB
  const int bl = blockIdx.x;
  const int b = bl >> 1, r = bl & 1;
  const int tid = threadIdx.x;
  const unsigned* sk = (r == 0) ? sub1 : sub2;
  const unsigned ka = sk[2*b], kb = sk[2*b+1];
  for (int i = tid; i < NN; i += 1024) {
    TF t = tf2(ka, kb, 0u, (unsigned)i);
    // composite (key<<32)|position => stable sort incl. key collisions
    s[i] = ((unsigned long long)(t.a ^ t.b) << 32) | (unsigned)i;
  }
  bitonic8192(s, tid);
  if (r == 0) {
    unsigned* v1 = v1buf + (size_t)b * NN;
    for (int i = tid; i < NN; i += 1024) v1[i] = (unsigned)(s[i] & 0xffffffffu);
  } else {
    for (int t = tid; t < NRAND; t += 1024)
      idx[b * NM + NFPS + t] = (int)(s[t] & 0xffffffffu);
  }
}

// ---------------- pos_sub gather (composes v1[v2] for the random part) ----------------
__global__ void possub_kernel(const float* __restrict__ pos,
                              const int* __restrict__ idx,
                              const unsigned* __restrict__ v1,
                              float* __restrict__ posOut) {
  int i = blockIdx.x * 256 + threadIdx.x;
  if (i >= NB * 3 * NM) return;
  int mm = i & (NM - 1);
  int bd = i >> 11;            // b*3 + d
  int d = bd % 3, b = bd / 3;
  int raw = idx[b * NM + mm];
  int id = (mm < NFPS) ? raw : (int)v1[(size_t)b * NN + raw];
  posOut[i] = pos[((size_t)b * 3 + d) * NN + id];
}

// ---------------- transpose x [B,C,N] -> xT [B,N,C] ----------------
__global__ void transpose_kernel(const float* __restrict__ x, float* __restrict__ xT) {
  __shared__ float t[32][33];
  int b = blockIdx.z;
  int n0 = blockIdx.x * 32, c0 = blockIdx.y * 32;
  int tx = threadIdx.x, ty = threadIdx.y;
  t[ty][tx] = x[((size_t)b * NC + (c0 + ty)) * NN + n0 + tx];
  __syncthreads();
  xT[((size_t)b * NN + (n0 + ty)) * NC + c0 + tx] = t[tx][ty];
}

// ---------------- KNN: one wave per sampled point ----------------
// Per-lane top-16 held in REGISTERS (float keys, branchless v_med3_f32 chain;
// stability-by-insertion-order gives exact tie semantics). LDS only for the
// final 64-list wave merge. Note: d2 self-distance is always +0.0 (a-a with
// rn), so the float->u32 order-flip at merge time is a total-order match.
__global__ __launch_bounds__(256) void knn_kernel(const float* __restrict__ pos,
                                                  const float* __restrict__ posSub,
                                                  int* __restrict__ knn) {
  __shared__ unsigned long long lst[4][NK][64]; // [wave][rank][lane], 32 KB
  const int tid = threadIdx.x;
  const int wv = tid >> 6, lane = tid & 63;
  const int g = blockIdx.x * 4 + wv;            // 0..16383
  const int b = g >> 11, mm = g & (NM - 1);
  const float* pb = pos + (size_t)b * 3 * NN;
  const float* ps = posSub + (size_t)b * 3 * NM;
  const float sx = ps[mm], sy = ps[NM + mm], sz = ps[2 * NM + mm];
  const float sm = __fadd_rn(__fadd_rn(__fmul_rn(sx, sx), __fmul_rn(sy, sy)),
                             __fmul_rn(sz, sz));
  float key[NK]; int kid[NK];
#pragma unroll
  for (int i = 0; i < NK; ++i) { key[i] = __int_as_float(0x7F800000); kid[i] = 0; }
  for (int t = 0; t < NN / 64; ++t) {
    const int n = t * 64 + lane;
    float x = pb[n], y = pb[NN + n], z = pb[2 * NN + n];
    float sn = __fadd_rn(__fadd_rn(__fmul_rn(x, x), __fmul_rn(y, y)), __fmul_rn(z, z));
    float dt = __fadd_rn(__fadd_rn(__fmul_rn(sx, x), __fmul_rn(sy, y)), __fmul_rn(sz, z));
    float d2 = __fsub_rn(__fadd_rn(sm, sn), __fmul_rn(2.0f, dt)); // mirror reference
    const float ck = d2; const int ci = n;
    // branchless sorted insert, descending so olds are read before overwrite;
    // strict < => equal keys keep earlier (smaller-index) candidate first
#pragma unroll
    for (int i = NK - 1; i >= 1; --i) {
      float lo = key[i-1], hi = key[i];
      bool cLo = ck < lo, cHi = ck < hi;
      key[i] = __builtin_amdgcn_fmed3f(ck, lo, hi);
      kid[i] = cLo ? kid[i-1] : (cHi ? ci : kid[i]);
    }
    bool c0 = ck < key[0];
    kid[0] = c0 ? ci : kid[0];
    key[0] = fminf(key[0], ck);
  }
  // dump sorted lists (order-flipped keys) to LDS; same-wave access, no barrier
#pragma unroll
  for (int i = 0; i < NK; ++i) {
    unsigned u = __float_as_uint(key[i]);
    u = (u & 0x80000000u) ? ~u : (u | 0x80000000u);
    lst[wv][i][lane] = ((unsigned long long)u << 32) | (unsigned)kid[i];
  }
  // merge 64 sorted lists: 16 rounds of wave-min; unique composites => safe pop
  int ptr = 0;
  unsigned long long head = lst[wv][0][lane];
  unsigned myn = 0;
  for (int k = 0; k < NK; ++k) {
    unsigned long long mn = head;
#pragma unroll
    for (int off = 32; off > 0; off >>= 1) {
      unsigned long long o = __shfl_xor(mn, off, 64);
      if (o < mn) mn = o;
    }
    if (head == mn) { ++ptr; head = (ptr < NK) ? lst[wv][ptr][lane] : ~0ull; }
    if (lane == k) myn = (unsigned)(mn & 0xffffffffu);
  }
  if (lane < NK) knn[(size_t)g * NK + lane] = (int)myn;
}

// ---------------- weights + gather + weighted sum ----------------
__global__ __launch_bounds__(256) void final_kernel(const float* __restrict__ xT,
                                                    const float* __restrict__ pos,
                                                    const float* __restrict__ posSub,
                                                    const int* __restrict__ knn,
                                                    float* __restrict__ xOut) {
  __shared__ float tile[64][17];
  const int tid = threadIdx.x;
  const int wv = tid >> 6, lane = tid & 63;
  const int base = blockIdx.x * 16;      // 16 consecutive samples, same batch
  const int b = base >> 11;
  const float* pb = pos + (size_t)b * 3 * NN;
  const float* ps = posSub + (size_t)b * 3 * NM;
  for (int j = 0; j < 4; ++j) {
    const int ml = wv * 4 + j;           // 0..15
    const int g = base + ml;
    const int mm = g & (NM - 1);
    const float sx = ps[mm], sy = ps[NM + mm], sz = ps[2 * NM + mm];
    const int kk = lane & 15;
    const int nk = knn[(size_t)g * NK + kk];
    float dx = __fsub_rn(pb[nk], sx);
    float dy = __fsub_rn(pb[NN + nk], sy);
    float dz = __fsub_rn(pb[2 * NN + nk], sz);
    float dd = __fadd_rn(__fadd_rn(__fmul_rn(dx, dx), __fmul_rn(dy, dy)),
                         __fmul_rn(dz, dz));
    float d = __fsqrt_rn(dd);
    d = fmaxf(d, 1e-6f);
    float e = __fdiv_rn(0.0f - d, 0.2f);
    float mx = e;
#pragma unroll
    for (int off = 8; off > 0; off >>= 1) mx = fmaxf(mx, __shfl_xor(mx, off, 16));
    float ex = expf(__fsub_rn(e, mx));
    float sum = ex;
#pragma unroll
    for (int off = 8; off > 0; off >>= 1) sum = __fadd_rn(sum, __shfl_xor(sum, off, 16));
    float wgt = __fdiv_rn(ex, sum);
    float acc = 0.0f;
#pragma unroll
    for (int k = 0; k < NK; ++k) {
      float wk = __shfl(wgt, k, 64);
      int   nn = __shfl(nk, k, 64);
      acc = __fadd_rn(acc, __fmul_rn(wk, xT[((size_t)b * NN + nn) * NC + lane]));
    }
    tile[lane][ml] = acc;
  }
  __syncthreads();
  const int m0 = base & (NM - 1);
  for (int e2 = tid; e2 < 64 * 16; e2 += 256) {
    int c = e2 >> 4, ml = e2 & 15;
    xOut[((size_t)b * NC + c) * NM + m0 + ml] = tile[c][ml];
  }
}

extern "C" void kernel_launch(void* const* d_in, const int* in_sizes, int n_in,
                              void* d_out, int out_size, void* d_ws, size_t ws_size,
                              hipStream_t stream) {
  const float* x   = (const float*)d_in[0];
  const float* pos = (const float*)d_in[1];
  float* xOut   = (float*)d_out;
  float* posOut = xOut + (size_t)NB * NC * NM;

  char* w = (char*)d_ws;
  unsigned* startB = (unsigned*)(w + OFF_START);
  unsigned* sub1   = (unsigned*)(w + OFF_SUB1);
  unsigned* sub2   = (unsigned*)(w + OFF_SUB2);
  int*      idx    = (int*)(w + OFF_IDX);
  unsigned* v1     = (unsigned*)(w + OFF_V1);
  int*      knn    = (int*)(w + OFF_KNN);
  float*    xT     = (float*)(w + OFF_XT);

  hipLaunchKernelGGL(rng_setup, dim3(1), dim3(64), 0, stream, startB, sub1, sub2);
  hipLaunchKernelGGL(fps_kernel, dim3(NB), dim3(256), 0, stream, pos, startB, idx);
  hipLaunchKernelGGL(perm_kernel, dim3(2 * NB), dim3(1024), 0, stream, sub1, sub2, v1, idx);
  hipLaunchKernelGGL(possub_kernel, dim3((NB * 3 * NM + 255) / 256), dim3(256), 0, stream,
                     pos, idx, v1, posOut);
  hipLaunchKernelGGL(transpose_kernel, dim3(NN / 32, NC / 32, NB), dim3(32, 32), 0, stream,
                     x, xT);
  hipLaunchKernelGGL(knn_kernel, dim3(NB * NM / 4), dim3(256), 0, stream, pos, posOut, knn);
  hipLaunchKernelGGL(final_kernel, dim3(NB * NM / 16), dim3(256), 0, stream,
                     xT, pos, posOut, knn, xOut);
}

// Round 4
// 1971.346 us; speedup vs baseline: 2.4559x; 1.3611x over previous
//
#include <hip/hip_runtime.h>

// Problem constants (match reference)
constexpr int NB   = 8;     // batches
constexpr int NC   = 64;    // channels
constexpr int NN   = 8192;  // points
constexpr int NM   = 2048;  // samples
constexpr int NK   = 16;    // knn
constexpr int NFPS = 1433;  // int(2048*0.7)
constexpr int NRAND = NM - NFPS; // 615

// ---------------- workspace layout (bytes) ----------------
constexpr size_t OFF_START = 0;
constexpr size_t OFF_SUB1  = 64;
constexpr size_t OFF_SUB2  = 128;
constexpr size_t OFF_IDX   = 256;      // int idx[8][2048]
constexpr size_t OFF_V1    = 66048;    // uint v1[8][8192]
constexpr size_t OFF_KNN   = 328448;   // int knn[8][2048][16]
constexpr size_t OFF_XT    = 1377280;  // float xT[8][8192][64]

struct TF { unsigned a, b; };

__device__ __forceinline__ TF tf2(unsigned k0, unsigned k1, unsigned c0, unsigned c1) {
  unsigned ks2 = k0 ^ k1 ^ 0x1BD11BDAu;
  unsigned x0 = c0 + k0;
  unsigned x1 = c1 + k1;
#define TF_R(r) { x0 += x1; x1 = (x1 << r) | (x1 >> (32 - r)); x1 ^= x0; }
  TF_R(13) TF_R(15) TF_R(26) TF_R(6)
  x0 += k1;  x1 += ks2 + 1u;
  TF_R(17) TF_R(29) TF_R(16) TF_R(24)
  x0 += ks2; x1 += k0 + 2u;
  TF_R(13) TF_R(15) TF_R(26) TF_R(6)
  x0 += k0;  x1 += k1 + 3u;
  TF_R(17) TF_R(29) TF_R(16) TF_R(24)
  x0 += k1;  x1 += ks2 + 4u;
  TF_R(13) TF_R(15) TF_R(26) TF_R(6)
  x0 += ks2; x1 += k0 + 5u;
#undef TF_R
  TF r; r.a = x0; r.b = x1; return r;
}

// ---------------- PRNG setup (jax_threefry_partitionable=True, verified R1) ----------------
__global__ void rng_setup(unsigned* __restrict__ startB,
                          unsigned* __restrict__ sub1,
                          unsigned* __restrict__ sub2) {
  if (threadIdx.x != 0) return;
  const unsigned K0 = 0u, K1 = 42u; // jax.random.key(42)
  for (int b = 0; b < NB; ++b) {
    TF kb = tf2(K0, K1, 0u, (unsigned)b);
    TF k2 = tf2(kb.a, kb.b, 0u, 1u);
    TF bt = tf2(k2.a, k2.b, 0u, 0u);
    startB[b] = (bt.a ^ bt.b) & (unsigned)(NN - 1);
  }
  TF keyr = tf2(K0, K1, 0u, 1u); // fold_in(key42, 1)
  for (int b = 0; b < NB; ++b) {
    TF rk = tf2(keyr.a, keyr.b, 0u, (unsigned)b);   // rkeys[b]
    TF s1 = tf2(rk.a, rk.b, 0u, 1u);                // round-1 subkey
    TF nk = tf2(rk.a, rk.b, 0u, 0u);                // round-1 carried key
    TF s2 = tf2(nk.a, nk.b, 0u, 1u);                // round-2 subkey
    sub1[2*b] = s1.a; sub1[2*b+1] = s1.b;
    sub2[2*b] = s2.a; sub2[2*b+1] = s2.b;
  }
}

// DPP-based wave64 max (VALU latency, no LDS on the chain).
// row_shr:1/2/4/8 build per-row(16) prefix max; row_bcast15 (rows 1,3) and
// row_bcast31 (rows 2,3) merge rows; lane 63 holds the full-wave max.
__device__ __forceinline__ float wave_max_dpp(float v) {
  int vi;
  vi = __builtin_amdgcn_update_dpp(__float_as_int(v), __float_as_int(v), 0x111, 0xf, 0xf, false);
  v = fmaxf(v, __int_as_float(vi));
  vi = __builtin_amdgcn_update_dpp(__float_as_int(v), __float_as_int(v), 0x112, 0xf, 0xf, false);
  v = fmaxf(v, __int_as_float(vi));
  vi = __builtin_amdgcn_update_dpp(__float_as_int(v), __float_as_int(v), 0x114, 0xf, 0xf, false);
  v = fmaxf(v, __int_as_float(vi));
  vi = __builtin_amdgcn_update_dpp(__float_as_int(v), __float_as_int(v), 0x118, 0xf, 0xf, false);
  v = fmaxf(v, __int_as_float(vi));
  vi = __builtin_amdgcn_update_dpp(__float_as_int(v), __float_as_int(v), 0x142, 0xa, 0xf, false);
  v = fmaxf(v, __int_as_float(vi));
  vi = __builtin_amdgcn_update_dpp(__float_as_int(v), __float_as_int(v), 0x143, 0xc, 0xf, false);
  v = fmaxf(v, __int_as_float(vi));
  return __int_as_float(__builtin_amdgcn_readlane(__float_as_int(v), 63));
}

// ---------------- FPS: one block (256 thr, 4 waves) per batch ----------------
// 1432 serial argmax steps. Per step: 32-slot register dist update (12 ops) ->
// DPP wave max + ballot/ctz/readlane arg -> 1-of-4 LDS slot -> ONE barrier
// (parity double-buffer) -> 3-way compare -> uniform LDS coord fetch.
// Tie-break = first index exactly (lane order == index order; wave0 first).
__global__ __launch_bounds__(256, 1) void fps_kernel(const float* __restrict__ pos,
                                                     const unsigned* __restrict__ startB,
                                                     int* __restrict__ idx) {
  __shared__ float ldsX[NN];   // 32 KB
  __shared__ float ldsY[NN];   // 32 KB
  __shared__ float ldsZ[NN];   // 32 KB
  __shared__ float2 slot[2][4];
  const int b = blockIdx.x;
  const int tid = threadIdx.x;
  const int wv = tid >> 6, lane = tid & 63;
  const float* pb = pos + (size_t)b * 3 * NN;
  float px[32], py[32], pz[32], dist[32];
  const int base = tid * 32;   // tid-major ownership => lane order == index order
  const float4* fx = (const float4*)(pb + base);
  const float4* fy = (const float4*)(pb + NN + base);
  const float4* fz = (const float4*)(pb + 2 * NN + base);
#pragma unroll
  for (int q = 0; q < 8; ++q) {
    float4 a = fx[q], c = fy[q], e = fz[q];
    px[4*q] = a.x; px[4*q+1] = a.y; px[4*q+2] = a.z; px[4*q+3] = a.w;
    py[4*q] = c.x; py[4*q+1] = c.y; py[4*q+2] = c.z; py[4*q+3] = c.w;
    pz[4*q] = e.x; pz[4*q+1] = e.y; pz[4*q+2] = e.z; pz[4*q+3] = e.w;
    ((float4*)(ldsX + base))[q] = a;   // one-time stage (conflicts OK, ~1 µs)
    ((float4*)(ldsY + base))[q] = c;
    ((float4*)(ldsZ + base))[q] = e;
  }
#pragma unroll
  for (int s = 0; s < 32; ++s) dist[s] = 1e10f;
  int widx = (int)startB[b];
  if (tid == 0) idx[b * NM] = widx;
  __syncthreads();
  float cx = ldsX[widx], cy = ldsY[widx], cz = ldsZ[widx];
  for (int it = 1; it < NFPS; ++it) {
    const int par = it & 1;
    float bestv = -1.0f; int bestS = 0;
#pragma unroll
    for (int s = 0; s < 32; ++s) {
      // Mirror numpy/XLA exactly: rn ops, no FMA contraction, ((dx2+dy2)+dz2)
      float dx = __fsub_rn(px[s], cx);
      float dy = __fsub_rn(py[s], cy);
      float dz = __fsub_rn(pz[s], cz);
      float d  = __fadd_rn(__fadd_rn(__fmul_rn(dx, dx), __fmul_rn(dy, dy)),
                           __fmul_rn(dz, dz));
      float nd = fminf(dist[s], d);
      dist[s] = nd;
      bool c = nd > bestv;            // strict > keeps first (smallest) index
      bestv = c ? nd : bestv;
      bestS = c ? s : bestS;
    }
    const int gidx = base + bestS;
    const float wm = wave_max_dpp(bestv);
    unsigned long long msk = __ballot(bestv == wm);  // nonzero: max lane matches
    const int fl = (int)__builtin_ctzll(msk);        // lowest lane = smallest index
    const int widxw = __builtin_amdgcn_readlane(gidx, fl);
    if (lane == 0) slot[par][wv] = make_float2(wm, __int_as_float(widxw));
    __syncthreads();
    float2 s0 = slot[par][0], s1 = slot[par][1], s2 = slot[par][2], s3 = slot[par][3];
    if (s1.x > s0.x) s0 = s1;     // ties keep lower wave = smaller index
    if (s3.x > s2.x) s2 = s3;
    if (s2.x > s0.x) s0 = s2;
    widx = __float_as_int(s0.y);
    cx = ldsX[widx]; cy = ldsY[widx]; cz = ldsZ[widx];  // uniform broadcast reads
    if (tid == 0) idx[b * NM + it] = widx;
  }
}

// ---------------- permutation: 2 independent stable sorts, 16 blocks ----------------
__device__ void bitonic8192(unsigned long long* s, int tid) {
  for (unsigned k = 2; k <= 8192u; k <<= 1) {
    for (unsigned j = k >> 1; j > 0; j >>= 1) {
      __syncthreads();
      for (unsigned t = (unsigned)tid; t < 4096u; t += 1024u) {
        unsigned i = ((t & ~(j - 1u)) << 1) | (t & (j - 1u));
        unsigned p = i | j;
        bool up = ((i & k) == 0u);
        unsigned long long a = s[i], c = s[p];
        if ((a > c) == up) { s[i] = c; s[p] = a; }
      }
    }
  }
  __syncthreads();
}

// block = (batch, round). Round 0 writes the full round-1 permutation v1;
// round 1 writes its first NRAND payload positions into idx (composed later).
__global__ __launch_bounds__(1024) void perm_kernel(const unsigned* __restrict__ sub1,
                                                    const unsigned* __restrict__ sub2,
                                                    unsigned* __restrict__ v1buf,
                                                    int* __restrict__ idx) {
  __shared__ unsigned long long s[NN]; // 64 KB
  const int bl = blockIdx.x;
  const int b = bl >> 1, r = bl & 1;
  const int tid = threadIdx.x;
  const unsigned* sk = (r == 0) ? sub1 : sub2;
  const unsigned ka = sk[2*b], kb = sk[2*b+1];
  for (int i = tid; i < NN; i += 1024) {
    TF t = tf2(ka, kb, 0u, (unsigned)i);
    // composite (key<<32)|position => stable sort incl. key collisions
    s[i] = ((unsigned long long)(t.a ^ t.b) << 32) | (unsigned)i;
  }
  bitonic8192(s, tid);
  if (r == 0) {
    unsigned* v1 = v1buf + (size_t)b * NN;
    for (int i = tid; i < NN; i += 1024) v1[i] = (unsigned)(s[i] & 0xffffffffu);
  } else {
    for (int t = tid; t < NRAND; t += 1024)
      idx[b * NM + NFPS + t] = (int)(s[t] & 0xffffffffu);
  }
}

// ---------------- pos_sub gather (composes v1[v2] for the random part) ----------------
__global__ void possub_kernel(const float* __restrict__ pos,
                              const int* __restrict__ idx,
                              const unsigned* __restrict__ v1,
                              float* __restrict__ posOut) {
  int i = blockIdx.x * 256 + threadIdx.x;
  if (i >= NB * 3 * NM) return;
  int mm = i & (NM - 1);
  int bd = i >> 11;            // b*3 + d
  int d = bd % 3, b = bd / 3;
  int raw = idx[b * NM + mm];
  int id = (mm < NFPS) ? raw : (int)v1[(size_t)b * NN + raw];
  posOut[i] = pos[((size_t)b * 3 + d) * NN + id];
}

// ---------------- transpose x [B,C,N] -> xT [B,N,C] ----------------
__global__ void transpose_kernel(const float* __restrict__ x, float* __restrict__ xT) {
  __shared__ float t[32][33];
  int b = blockIdx.z;
  int n0 = blockIdx.x * 32, c0 = blockIdx.y * 32;
  int tx = threadIdx.x, ty = threadIdx.y;
  t[ty][tx] = x[((size_t)b * NC + (c0 + ty)) * NN + n0 + tx];
  __syncthreads();
  xT[((size_t)b * NN + (n0 + ty)) * NC + c0 + tx] = t[tx][ty];
}

// ---------------- KNN: one wave per sampled point ----------------
// Per-lane top-16 in registers (branchless v_med3 chain); LDS only for the
// final 64-list wave merge (verified R3).
__global__ __launch_bounds__(256) void knn_kernel(const float* __restrict__ pos,
                                                  const float* __restrict__ posSub,
                                                  int* __restrict__ knn) {
  __shared__ unsigned long long lst[4][NK][64]; // [wave][rank][lane], 32 KB
  const int tid = threadIdx.x;
  const int wv = tid >> 6, lane = tid & 63;
  const int g = blockIdx.x * 4 + wv;            // 0..16383
  const int b = g >> 11, mm = g & (NM - 1);
  const float* pb = pos + (size_t)b * 3 * NN;
  const float* ps = posSub + (size_t)b * 3 * NM;
  const float sx = ps[mm], sy = ps[NM + mm], sz = ps[2 * NM + mm];
  const float sm = __fadd_rn(__fadd_rn(__fmul_rn(sx, sx), __fmul_rn(sy, sy)),
                             __fmul_rn(sz, sz));
  float key[NK]; int kid[NK];
#pragma unroll
  for (int i = 0; i < NK; ++i) { key[i] = __int_as_float(0x7F800000); kid[i] = 0; }
  for (int t = 0; t < NN / 64; ++t) {
    const int n = t * 64 + lane;
    float x = pb[n], y = pb[NN + n], z = pb[2 * NN + n];
    float sn = __fadd_rn(__fadd_rn(__fmul_rn(x, x), __fmul_rn(y, y)), __fmul_rn(z, z));
    float dt = __fadd_rn(__fadd_rn(__fmul_rn(sx, x), __fmul_rn(sy, y)), __fmul_rn(sz, z));
    float d2 = __fsub_rn(__fadd_rn(sm, sn), __fmul_rn(2.0f, dt)); // mirror reference
    const float ck = d2; const int ci = n;
    // branchless sorted insert, descending so olds are read before overwrite;
    // strict < => equal keys keep earlier (smaller-index) candidate first
#pragma unroll
    for (int i = NK - 1; i >= 1; --i) {
      float lo = key[i-1], hi = key[i];
      bool cLo = ck < lo, cHi = ck < hi;
      key[i] = __builtin_amdgcn_fmed3f(ck, lo, hi);
      kid[i] = cLo ? kid[i-1] : (cHi ? ci : kid[i]);
    }
    bool c0 = ck < key[0];
    kid[0] = c0 ? ci : kid[0];
    key[0] = fminf(key[0], ck);
  }
  // dump sorted lists (order-flipped keys) to LDS; same-wave access, no barrier
#pragma unroll
  for (int i = 0; i < NK; ++i) {
    unsigned u = __float_as_uint(key[i]);
    u = (u & 0x80000000u) ? ~u : (u | 0x80000000u);
    lst[wv][i][lane] = ((unsigned long long)u << 32) | (unsigned)kid[i];
  }
  // merge 64 sorted lists: 16 rounds of wave-min; unique composites => safe pop
  int ptr = 0;
  unsigned long long head = lst[wv][0][lane];
  unsigned myn = 0;
  for (int k = 0; k < NK; ++k) {
    unsigned long long mn = head;
#pragma unroll
    for (int off = 32; off > 0; off >>= 1) {
      unsigned long long o = __shfl_xor(mn, off, 64);
      if (o < mn) mn = o;
    }
    if (head == mn) { ++ptr; head = (ptr < NK) ? lst[wv][ptr][lane] : ~0ull; }
    if (lane == k) myn = (unsigned)(mn & 0xffffffffu);
  }
  if (lane < NK) knn[(size_t)g * NK + lane] = (int)myn;
}

// ---------------- weights + gather + weighted sum ----------------
__global__ __launch_bounds__(256) void final_kernel(const float* __restrict__ xT,
                                                    const float* __restrict__ pos,
                                                    const float* __restrict__ posSub,
                                                    const int* __restrict__ knn,
                                                    float* __restrict__ xOut) {
  __shared__ float tile[64][17];
  const int tid = threadIdx.x;
  const int wv = tid >> 6, lane = tid & 63;
  const int base = blockIdx.x * 16;      // 16 consecutive samples, same batch
  const int b = base >> 11;
  const float* pb = pos + (size_t)b * 3 * NN;
  const float* ps = posSub + (size_t)b * 3 * NM;
  for (int j = 0; j < 4; ++j) {
    const int ml = wv * 4 + j;           // 0..15
    const int g = base + ml;
    const int mm = g & (NM - 1);
    const float sx = ps[mm], sy = ps[NM + mm], sz = ps[2 * NM + mm];
    const int kk = lane & 15;
    const int nk = knn[(size_t)g * NK + kk];
    float dx = __fsub_rn(pb[nk], sx);
    float dy = __fsub_rn(pb[NN + nk], sy);
    float dz = __fsub_rn(pb[2 * NN + nk], sz);
    float dd = __fadd_rn(__fadd_rn(__fmul_rn(dx, dx), __fmul_rn(dy, dy)),
                         __fmul_rn(dz, dz));
    float d = __fsqrt_rn(dd);
    d = fmaxf(d, 1e-6f);
    float e = __fdiv_rn(0.0f - d, 0.2f);
    float mx = e;
#pragma unroll
    for (int off = 8; off > 0; off >>= 1) mx = fmaxf(mx, __shfl_xor(mx, off, 16));
    float ex = expf(__fsub_rn(e, mx));
    float sum = ex;
#pragma unroll
    for (int off = 8; off > 0; off >>= 1) sum = __fadd_rn(sum, __shfl_xor(sum, off, 16));
    float wgt = __fdiv_rn(ex, sum);
    float acc = 0.0f;
#pragma unroll
    for (int k = 0; k < NK; ++k) {
      float wk = __shfl(wgt, k, 64);
      int   nn = __shfl(nk, k, 64);
      acc = __fadd_rn(acc, __fmul_rn(wk, xT[((size_t)b * NN + nn) * NC + lane]));
    }
    tile[lane][ml] = acc;
  }
  __syncthreads();
  const int m0 = base & (NM - 1);
  for (int e2 = tid; e2 < 64 * 16; e2 += 256) {
    int c = e2 >> 4, ml = e2 & 15;
    xOut[((size_t)b * NC + c) * NM + m0 + ml] = tile[c][ml];
  }
}

extern "C" void kernel_launch(void* const* d_in, const int* in_sizes, int n_in,
                              void* d_out, int out_size, void* d_ws, size_t ws_size,
                              hipStream_t stream) {
  const float* x   = (const float*)d_in[0];
  const float* pos = (const float*)d_in[1];
  float* xOut   = (float*)d_out;
  float* posOut = xOut + (size_t)NB * NC * NM;

  char* w = (char*)d_ws;
  unsigned* startB = (unsigned*)(w + OFF_START);
  unsigned* sub1   = (unsigned*)(w + OFF_SUB1);
  unsigned* sub2   = (unsigned*)(w + OFF_SUB2);
  int*      idx    = (int*)(w + OFF_IDX);
  unsigned* v1     = (unsigned*)(w + OFF_V1);
  int*      knn    = (int*)(w + OFF_KNN);
  float*    xT     = (float*)(w + OFF_XT);

  hipLaunchKernelGGL(rng_setup, dim3(1), dim3(64), 0, stream, startB, sub1, sub2);
  hipLaunchKernelGGL(fps_kernel, dim3(NB), dim3(256), 0, stream, pos, startB, idx);
  hipLaunchKernelGGL(perm_kernel, dim3(2 * NB), dim3(1024), 0, stream, sub1, sub2, v1, idx);
  hipLaunchKernelGGL(possub_kernel, dim3((NB * 3 * NM + 255) / 256), dim3(256), 0, stream,
                     pos, idx, v1, posOut);
  hipLaunchKernelGGL(transpose_kernel, dim3(NN / 32, NC / 32, NB), dim3(32, 32), 0, stream,
                     x, xT);
  hipLaunchKernelGGL(knn_kernel, dim3(NB * NM / 4), dim3(256), 0, stream, pos, posOut, knn);
  hipLaunchKernelGGL(final_kernel, dim3(NB * NM / 16), dim3(256), 0, stream,
                     xT, pos, posOut, knn, xOut);
}